// Round 1
// baseline (886.285 us; speedup 1.0000x reference)
//
#include <hip/hip_runtime.h>
#include <hip/hip_bf16.h>

#define N_NODES 100000
#define N_EDGES 1600000
#define BATCH   16384
#define HID     128
#define CHUNK   1024
#define NCHUNKS ((N_NODES + CHUNK - 1) / CHUNK)   // 98

// ---------------- CSR build ----------------

__global__ void k_hist(const int* __restrict__ dst, int* __restrict__ counts, int e) {
    int i = blockIdx.x * blockDim.x + threadIdx.x;
    if (i < e) atomicAdd(&counts[dst[i]], 1);
}

__global__ void k_scan1(const int* __restrict__ counts, int* __restrict__ chunkSum, int n) {
    __shared__ int sh[256];
    int t = threadIdx.x;
    int base = blockIdx.x * CHUNK + t * 4;
    int s = 0;
#pragma unroll
    for (int j = 0; j < 4; ++j) {
        int i = base + j;
        if (i < n) s += counts[i];
    }
    sh[t] = s;
    __syncthreads();
    for (int off = 128; off; off >>= 1) {
        if (t < off) sh[t] += sh[t + off];
        __syncthreads();
    }
    if (t == 0) chunkSum[blockIdx.x] = sh[0];
}

__global__ void k_scan2(const int* __restrict__ chunkSum, int* __restrict__ chunkBase,
                        int* __restrict__ offsets, int nc, int n) {
    __shared__ int sh[128];
    __shared__ int bs[128];
    int t = threadIdx.x;
    if (t < nc) sh[t] = chunkSum[t];
    __syncthreads();
    if (t == 0) {
        int run = 0;
        for (int i = 0; i < nc; ++i) { bs[i] = run; run += sh[i]; }
        offsets[n] = run;   // == N_EDGES
    }
    __syncthreads();
    if (t < nc) chunkBase[t] = bs[t];
}

__global__ void k_scan3(const int* __restrict__ counts, const int* __restrict__ chunkBase,
                        int* __restrict__ offsets, int n) {
    __shared__ int sh[256];
    int t = threadIdx.x;
    int base = blockIdx.x * CHUNK + t * 4;
    int c[4];
#pragma unroll
    for (int j = 0; j < 4; ++j) {
        int i = base + j;
        c[j] = (i < n) ? counts[i] : 0;
    }
    int tot = c[0] + c[1] + c[2] + c[3];
    sh[t] = tot;
    __syncthreads();
    // Hillis-Steele inclusive scan over 256 thread-sums
    for (int off = 1; off < 256; off <<= 1) {
        int v = 0;
        if (t >= off) v = sh[t - off];
        __syncthreads();
        if (t >= off) sh[t] += v;
        __syncthreads();
    }
    int excl = sh[t] - tot;
    int gbase = chunkBase[blockIdx.x] + excl;
    int pre = 0;
#pragma unroll
    for (int j = 0; j < 4; ++j) {
        int i = base + j;
        if (i < n) offsets[i] = gbase + pre;
        pre += c[j];
    }
}

__global__ void k_dinv(const int* __restrict__ counts, float* __restrict__ dinv, int n) {
    int i = blockIdx.x * blockDim.x + threadIdx.x;
    if (i < n) dinv[i] = rsqrtf((float)counts[i] + 1.0f);   // +1 self-loop
}

__global__ void k_scatter(const int* __restrict__ edge, int* __restrict__ cursor,
                          int* __restrict__ col, int e) {
    int i = blockIdx.x * blockDim.x + threadIdx.x;
    if (i < e) {
        int d = edge[N_EDGES + i];
        int pos = atomicAdd(&cursor[d], 1);
        col[pos] = edge[i];
    }
}

// ---------------- GEMM: out[M,128] = A[gather][:,128] @ W[128,128] (+bias) (+= out) ----------------
// BM=64, BN=128, BK=16; 256 threads; each thread 4 rows x 8 cols.

__global__ __launch_bounds__(256) void k_gemm128(
    const float* __restrict__ A, const float* __restrict__ W,
    float* __restrict__ out, const int* __restrict__ gidx,
    const float* __restrict__ bias, int M, int accumulate) {
    __shared__ float Xt[16][64];    // k-major transposed X tile
    __shared__ float Ws[16][128];

    int tid = threadIdx.x;
    int tc = tid & 15, tr = tid >> 4;
    int r0 = tr << 2, c0 = tc << 2;
    float acc[4][8];
#pragma unroll
    for (int i = 0; i < 4; ++i)
#pragma unroll
        for (int j = 0; j < 8; ++j) acc[i][j] = 0.f;

    int rowBase = blockIdx.x << 6;
    int sr = tid >> 2, sq = tid & 3;
    int arowi = rowBase + sr;
    long long arow = -1;
    if (arowi < M) arow = gidx ? (long long)gidx[arowi] : (long long)arowi;

    int k0 = tid >> 5;              // 0..7
    int cc0 = (tid & 31) << 2;
    int k1 = k0 + 8;                // 8..15

    for (int kk = 0; kk < 128; kk += 16) {
        float4 xv = make_float4(0.f, 0.f, 0.f, 0.f);
        if (arow >= 0) xv = *(const float4*)&A[(size_t)arow * 128 + kk + (sq << 2)];
        float4 w0 = *(const float4*)&W[(size_t)(kk + k0) * 128 + cc0];
        float4 w1 = *(const float4*)&W[(size_t)(kk + k1) * 128 + cc0];
        __syncthreads();
        Xt[(sq << 2) + 0][sr] = xv.x;
        Xt[(sq << 2) + 1][sr] = xv.y;
        Xt[(sq << 2) + 2][sr] = xv.z;
        Xt[(sq << 2) + 3][sr] = xv.w;
        *(float4*)&Ws[k0][cc0] = w0;
        *(float4*)&Ws[k1][cc0] = w1;
        __syncthreads();
#pragma unroll
        for (int k = 0; k < 16; ++k) {
            float4 xa = *(const float4*)&Xt[k][r0];
            float4 b0 = *(const float4*)&Ws[k][c0];
            float4 b1 = *(const float4*)&Ws[k][c0 + 64];
            float av[4] = {xa.x, xa.y, xa.z, xa.w};
            float bv[8] = {b0.x, b0.y, b0.z, b0.w, b1.x, b1.y, b1.z, b1.w};
#pragma unroll
            for (int i = 0; i < 4; ++i)
#pragma unroll
                for (int j = 0; j < 8; ++j)
                    acc[i][j] = fmaf(av[i], bv[j], acc[i][j]);
        }
    }

#pragma unroll
    for (int i = 0; i < 4; ++i) {
        int r = rowBase + r0 + i;
        if (r < M) {
            float* orow = out + (size_t)r * 128;
#pragma unroll
            for (int j = 0; j < 4; ++j) {
                int cA = c0 + j, cB = c0 + 64 + j;
                float v1 = acc[i][j], v2 = acc[i][j + 4];
                if (bias) { v1 += bias[cA]; v2 += bias[cB]; }
                if (accumulate) { v1 += orow[cA]; v2 += orow[cB]; }
                orow[cA] = v1;
                orow[cB] = v2;
            }
        }
    }
}

// ---------------- Aggregation: one wave per dst node ----------------
// xout[v] = relu((sum_{e:dst=v} h[col[e]]*dinv[col[e]] + h[v]*dinv[v]) * dinv[v] + bias)

__global__ __launch_bounds__(256) void k_agg(
    const float* __restrict__ h, const int* __restrict__ col,
    const int* __restrict__ offs, const float* __restrict__ dinv,
    const float* __restrict__ bias, float* __restrict__ xout, int n) {
    int lane = threadIdx.x & 63;
    int v = (blockIdx.x << 2) + (threadIdx.x >> 6);
    if (v >= n) return;
    int beg = offs[v], end = offs[v + 1];
    float dv = dinv[v];
    float2 hv = *(const float2*)&h[(size_t)v * 128 + lane * 2];
    float ax = hv.x * dv, ay = hv.y * dv;
    int s_next = (beg < end) ? col[beg] : 0;
    for (int e = beg; e < end; ++e) {
        int s = s_next;
        if (e + 1 < end) s_next = col[e + 1];
        float w = dinv[s];
        float2 hs = *(const float2*)&h[(size_t)s * 128 + lane * 2];
        ax = fmaf(hs.x, w, ax);
        ay = fmaf(hs.y, w, ay);
    }
    float2 bv = *(const float2*)&bias[lane * 2];
    float ox = fmaf(ax, dv, bv.x);
    float oy = fmaf(ay, dv, bv.y);
    ox = fmaxf(ox, 0.f);
    oy = fmaxf(oy, 0.f);
    *(float2*)&xout[(size_t)v * 128 + lane * 2] = make_float2(ox, oy);
}

// ---------------- Final dot: sv[b] = P[b,:] . Q[b,:] ----------------

__global__ __launch_bounds__(256) void k_dot(
    const float* __restrict__ P, const float* __restrict__ Q,
    float* __restrict__ out, int B) {
    int lane = threadIdx.x & 63;
    int b = (blockIdx.x << 2) + (threadIdx.x >> 6);
    if (b >= B) return;
    float2 p = *(const float2*)&P[(size_t)b * 128 + lane * 2];
    float2 q = *(const float2*)&Q[(size_t)b * 128 + lane * 2];
    float s = p.x * q.x + p.y * q.y;
#pragma unroll
    for (int off = 32; off; off >>= 1) s += __shfl_down(s, off);
    if (lane == 0) out[b] = s;
}

// ---------------- launch ----------------

extern "C" void kernel_launch(void* const* d_in, const int* in_sizes, int n_in,
                              void* d_out, int out_size, void* d_ws, size_t ws_size,
                              hipStream_t stream) {
    const float* x    = (const float*)d_in[0];
    const int*   edge = (const int*)d_in[1];     // [2][E]: row0=src, row1=dst
    const int*   sidx = (const int*)d_in[2];
    const int*   tidx = (const int*)d_in[3];
    const float* Wc0  = (const float*)d_in[4];
    const float* bc0  = (const float*)d_in[5];
    const float* Wc1  = (const float*)d_in[6];
    const float* bc1  = (const float*)d_in[7];
    const float* Wc2  = (const float*)d_in[8];
    const float* bc2  = (const float*)d_in[9];
    const float* Ww   = (const float*)d_in[10];
    const float* bw   = (const float*)d_in[11];
    const float* Wp   = (const float*)d_in[12];
    const float* bp   = (const float*)d_in[13];
    float* out = (float*)d_out;

    // workspace carve (256B aligned)
    char* base = (char*)d_ws;
    size_t off = 0;
    auto alloc = [&](size_t bytes) -> char* {
        char* p = base + off;
        off = (off + bytes + 255) & ~(size_t)255;
        return p;
    };
    const size_t FSZ = (size_t)N_NODES * HID * sizeof(float);   // 51.2 MB
    float* bufA   = (float*)alloc(FSZ);
    float* bufB   = (float*)alloc(FSZ);
    float* bufH   = (float*)alloc(FSZ);
    float* Pm     = (float*)alloc((size_t)BATCH * HID * sizeof(float));
    float* Qm     = (float*)alloc((size_t)BATCH * HID * sizeof(float));
    int*   counts = (int*)alloc((size_t)N_NODES * sizeof(int));
    int*   offsets= (int*)alloc((size_t)(N_NODES + 1) * sizeof(int));
    int*   cursor = (int*)alloc((size_t)N_NODES * sizeof(int));
    int*   colArr = (int*)alloc((size_t)N_EDGES * sizeof(int));
    float* dinv   = (float*)alloc((size_t)N_NODES * sizeof(float));
    int*   chunkSum  = (int*)alloc(512 * sizeof(int));
    int*   chunkBase = (int*)alloc(512 * sizeof(int));
    (void)ws_size; (void)in_sizes; (void)n_in; (void)out_size;

    // ---- CSR build ----
    hipMemsetAsync(counts, 0, (size_t)N_NODES * sizeof(int), stream);
    {
        int g = (N_EDGES + 255) / 256;
        k_hist<<<g, 256, 0, stream>>>(edge + N_EDGES, counts, N_EDGES);
    }
    k_scan1<<<NCHUNKS, 256, 0, stream>>>(counts, chunkSum, N_NODES);
    k_scan2<<<1, 128, 0, stream>>>(chunkSum, chunkBase, offsets, NCHUNKS, N_NODES);
    k_scan3<<<NCHUNKS, 256, 0, stream>>>(counts, chunkBase, offsets, N_NODES);
    k_dinv<<<(N_NODES + 255) / 256, 256, 0, stream>>>(counts, dinv, N_NODES);
    hipMemcpyAsync(cursor, offsets, (size_t)N_NODES * sizeof(int),
                   hipMemcpyDeviceToDevice, stream);
    {
        int g = (N_EDGES + 255) / 256;
        k_scatter<<<g, 256, 0, stream>>>(edge, cursor, colArr, N_EDGES);
    }

    const int gemmGridN = (N_NODES + 63) / 64;   // 1563
    const int gemmGridB = (BATCH + 63) / 64;     // 256
    const int aggGrid   = (N_NODES + 3) / 4;     // 25000
    const int dotGrid   = (BATCH + 3) / 4;       // 4096

    // ---- layer 1 ----
    k_gemm128<<<gemmGridN, 256, 0, stream>>>(x, Wc0, bufH, nullptr, nullptr, N_NODES, 0);
    k_agg<<<aggGrid, 256, 0, stream>>>(bufH, colArr, offsets, dinv, bc0, bufA, N_NODES);
    k_gemm128<<<gemmGridB, 256, 0, stream>>>(bufA, Wp, Pm, sidx, bp, BATCH, 0);
    k_gemm128<<<gemmGridB, 256, 0, stream>>>(bufA, Ww, Qm, tidx, bw, BATCH, 0);

    // ---- layer 2 ----
    k_gemm128<<<gemmGridN, 256, 0, stream>>>(bufA, Wc1, bufH, nullptr, nullptr, N_NODES, 0);
    k_agg<<<aggGrid, 256, 0, stream>>>(bufH, colArr, offsets, dinv, bc1, bufB, N_NODES);
    k_gemm128<<<gemmGridB, 256, 0, stream>>>(bufB, Wp + 128 * 128, Pm, sidx, nullptr, BATCH, 1);
    k_gemm128<<<gemmGridB, 256, 0, stream>>>(bufB, Ww + 128 * 128, Qm, tidx, nullptr, BATCH, 1);

    // ---- layer 3 ----
    k_gemm128<<<gemmGridN, 256, 0, stream>>>(bufB, Wc2, bufH, nullptr, nullptr, N_NODES, 0);
    k_agg<<<aggGrid, 256, 0, stream>>>(bufH, colArr, offsets, dinv, bc2, bufA, N_NODES);
    k_gemm128<<<gemmGridB, 256, 0, stream>>>(bufA, Wp + 2 * 128 * 128, Pm, sidx, nullptr, BATCH, 1);
    k_gemm128<<<gemmGridB, 256, 0, stream>>>(bufA, Ww + 2 * 128 * 128, Qm, tidx, nullptr, BATCH, 1);

    // ---- score ----
    k_dot<<<dotGrid, 256, 0, stream>>>(Pm, Qm, out, BATCH);
}

// Round 2
// 835.297 us; speedup vs baseline: 1.0610x; 1.0610x over previous
//
#include <hip/hip_runtime.h>
#include <hip/hip_bf16.h>

#define N_NODES 100000
#define N_EDGES 1600000
#define BATCH   16384
#define HID     128
#define CHUNK   1024
#define NCHUNKS ((N_NODES + CHUNK - 1) / CHUNK)   // 98

typedef __attribute__((ext_vector_type(8))) short bf16x8;
typedef __attribute__((ext_vector_type(4))) float fx4;

__device__ inline short f2bf(float f) {
    unsigned u = __builtin_bit_cast(unsigned, f);
    unsigned r = (u + 0x7FFF + ((u >> 16) & 1)) >> 16;
    return (short)r;
}
__device__ inline float bf2f(short s) {
    unsigned u = ((unsigned)(unsigned short)s) << 16;
    return __builtin_bit_cast(float, u);
}

// ---------------- CSR build (unchanged from round 0) ----------------

__global__ void k_hist(const int* __restrict__ dst, int* __restrict__ counts, int e) {
    int i = blockIdx.x * blockDim.x + threadIdx.x;
    if (i < e) atomicAdd(&counts[dst[i]], 1);
}

__global__ void k_scan1(const int* __restrict__ counts, int* __restrict__ chunkSum, int n) {
    __shared__ int sh[256];
    int t = threadIdx.x;
    int base = blockIdx.x * CHUNK + t * 4;
    int s = 0;
#pragma unroll
    for (int j = 0; j < 4; ++j) {
        int i = base + j;
        if (i < n) s += counts[i];
    }
    sh[t] = s;
    __syncthreads();
    for (int off = 128; off; off >>= 1) {
        if (t < off) sh[t] += sh[t + off];
        __syncthreads();
    }
    if (t == 0) chunkSum[blockIdx.x] = sh[0];
}

__global__ void k_scan2(const int* __restrict__ chunkSum, int* __restrict__ chunkBase,
                        int* __restrict__ offsets, int nc, int n) {
    __shared__ int sh[128];
    __shared__ int bs[128];
    int t = threadIdx.x;
    if (t < nc) sh[t] = chunkSum[t];
    __syncthreads();
    if (t == 0) {
        int run = 0;
        for (int i = 0; i < nc; ++i) { bs[i] = run; run += sh[i]; }
        offsets[n] = run;
    }
    __syncthreads();
    if (t < nc) chunkBase[t] = bs[t];
}

__global__ void k_scan3(const int* __restrict__ counts, const int* __restrict__ chunkBase,
                        int* __restrict__ offsets, int n) {
    __shared__ int sh[256];
    int t = threadIdx.x;
    int base = blockIdx.x * CHUNK + t * 4;
    int c[4];
#pragma unroll
    for (int j = 0; j < 4; ++j) {
        int i = base + j;
        c[j] = (i < n) ? counts[i] : 0;
    }
    int tot = c[0] + c[1] + c[2] + c[3];
    sh[t] = tot;
    __syncthreads();
    for (int off = 1; off < 256; off <<= 1) {
        int v = 0;
        if (t >= off) v = sh[t - off];
        __syncthreads();
        if (t >= off) sh[t] += v;
        __syncthreads();
    }
    int excl = sh[t] - tot;
    int gbase = chunkBase[blockIdx.x] + excl;
    int pre = 0;
#pragma unroll
    for (int j = 0; j < 4; ++j) {
        int i = base + j;
        if (i < n) offsets[i] = gbase + pre;
        pre += c[j];
    }
}

__global__ void k_dinv(const int* __restrict__ counts, float* __restrict__ dinv, int n) {
    int i = blockIdx.x * blockDim.x + threadIdx.x;
    if (i < n) dinv[i] = rsqrtf((float)counts[i] + 1.0f);
}

__global__ void k_scatter(const int* __restrict__ edge, int* __restrict__ cursor,
                          int* __restrict__ col, int e) {
    int i = blockIdx.x * blockDim.x + threadIdx.x;
    if (i < e) {
        int d = edge[N_EDGES + i];
        int pos = atomicAdd(&cursor[d], 1);
        col[pos] = edge[i];
    }
}

// ---------------- weight prep: split fp32 W[k][n] -> bf16 hi/lo, transposed WT[n][k] ----------------
// chunks: 0..2 = Wc0..Wc2; 3..5 = Wp rows [c*128,(c+1)*128); 6..8 = Ww likewise.

__global__ void k_prepW(const float* __restrict__ Wc0, const float* __restrict__ Wc1,
                        const float* __restrict__ Wc2, const float* __restrict__ Wp,
                        const float* __restrict__ Ww,
                        short* __restrict__ outH, short* __restrict__ outL) {
    int c = blockIdx.x;
    const float* src;
    int koff = 0;
    if (c == 0) src = Wc0;
    else if (c == 1) src = Wc1;
    else if (c == 2) src = Wc2;
    else if (c < 6) { src = Wp; koff = (c - 3) * 128; }
    else { src = Ww; koff = (c - 6) * 128; }
    short* dh = outH + c * 16384;
    short* dl = outL + c * 16384;
    for (int i = threadIdx.x; i < 16384; i += 256) {
        int k = i >> 7, n = i & 127;
        float v = src[(size_t)(koff + k) * 128 + n];
        short h = f2bf(v);
        short l = f2bf(v - bf2f(h));
        dh[n * 128 + k] = h;
        dl[n * 128 + k] = l;
    }
}

// ---------------- split-bf16 MFMA GEMM ----------------
// out[M,128] = A[gidx][:,128] @ W[128,128]  via  Ah@Wh + Ah@Wl + Al@Wh
// BM=64, BN=64 (ntile = blockIdx.x&1), 256 threads = 4 waves, wave tile 32x32
// epilogue: optional row scale (dinv), bias add, accumulate.

__global__ __launch_bounds__(256) void k_mgemm(
    const float* __restrict__ A, const short* __restrict__ WTh,
    const short* __restrict__ WTl, float* __restrict__ out,
    const int* __restrict__ gidx, const float* __restrict__ bias,
    const float* __restrict__ scale, int M, int accumulate) {
    __shared__ short Ah[64 * 128];
    __shared__ short Al[64 * 128];
    __shared__ short Bh[64 * 128];
    __shared__ short Bl[64 * 128];

    int t = threadIdx.x;
    int mtile = blockIdx.x >> 1, ntile = blockIdx.x & 1;
    int rowBase = mtile << 6;

    // ---- stage A: 64 rows x 128 k fp32 -> bf16 hi/lo, XOR-swizzled rows ----
#pragma unroll
    for (int j = 0; j < 8; ++j) {
        int row = (t >> 5) + (j << 3);
        int colf = (t & 31) << 2;
        int gr = rowBase + row;
        float4 v = make_float4(0.f, 0.f, 0.f, 0.f);
        if (gr < M) {
            long long ar = gidx ? (long long)gidx[gr] : (long long)gr;
            v = *(const float4*)&A[(size_t)ar * 128 + colf];
        }
        short4 hi, lo;
        hi.x = f2bf(v.x); lo.x = f2bf(v.x - bf2f(hi.x));
        hi.y = f2bf(v.y); lo.y = f2bf(v.y - bf2f(hi.y));
        hi.z = f2bf(v.z); lo.z = f2bf(v.z - bf2f(hi.z));
        hi.w = f2bf(v.w); lo.w = f2bf(v.w - bf2f(hi.w));
        unsigned off = (unsigned)(row << 8) + (((unsigned)(colf << 1)) ^ ((unsigned)((row & 7) << 4)));
        *(short4*)((char*)Ah + off) = hi;
        *(short4*)((char*)Al + off) = lo;
    }
    // ---- stage W^T: 64 cols x 128 k bf16, same swizzle ----
#pragma unroll
    for (int j = 0; j < 4; ++j) {
        int c = (t >> 4) + (j << 4);
        int k8 = (t & 15) << 3;
        size_t goff = ((size_t)((ntile << 6) + c) << 7) + k8;
        bf16x8 wh = *(const bf16x8*)&WTh[goff];
        bf16x8 wl = *(const bf16x8*)&WTl[goff];
        unsigned off = (unsigned)(c << 8) + (((unsigned)(k8 << 1)) ^ ((unsigned)((c & 7) << 4)));
        *(bf16x8*)((char*)Bh + off) = wh;
        *(bf16x8*)((char*)Bl + off) = wl;
    }
    __syncthreads();

    int lane = t & 63;
    int wave = t >> 6;
    int wm = wave >> 1, wn = wave & 1;
    int l15 = lane & 15;
    int kq = (lane >> 4) << 4;    // byte offset of this lane's 8-element k-slice

    fx4 acc[2][2];
#pragma unroll
    for (int i = 0; i < 2; ++i)
#pragma unroll
        for (int j = 0; j < 2; ++j) {
            acc[i][j][0] = 0.f; acc[i][j][1] = 0.f;
            acc[i][j][2] = 0.f; acc[i][j][3] = 0.f;
        }

    int ar0 = (wm << 5) + l15;
    int bc0 = (wn << 5) + l15;

#pragma unroll
    for (int k = 0; k < 4; ++k) {
        int kb = (k << 6) + kq;
        bf16x8 ah[2], al[2], bh[2], bl[2];
#pragma unroll
        for (int fr = 0; fr < 2; ++fr) {
            int r = ar0 + (fr << 4);
            unsigned off = (unsigned)(r << 8) + ((unsigned)kb ^ ((unsigned)((r & 7) << 4)));
            ah[fr] = *(const bf16x8*)((const char*)Ah + off);
            al[fr] = *(const bf16x8*)((const char*)Al + off);
        }
#pragma unroll
        for (int fc = 0; fc < 2; ++fc) {
            int c = bc0 + (fc << 4);
            unsigned off = (unsigned)(c << 8) + ((unsigned)kb ^ ((unsigned)((c & 7) << 4)));
            bh[fc] = *(const bf16x8*)((const char*)Bh + off);
            bl[fc] = *(const bf16x8*)((const char*)Bl + off);
        }
#pragma unroll
        for (int fr = 0; fr < 2; ++fr)
#pragma unroll
            for (int fc = 0; fc < 2; ++fc) {
                acc[fr][fc] = __builtin_amdgcn_mfma_f32_16x16x32_bf16(ah[fr], bh[fc], acc[fr][fc], 0, 0, 0);
                acc[fr][fc] = __builtin_amdgcn_mfma_f32_16x16x32_bf16(ah[fr], bl[fc], acc[fr][fc], 0, 0, 0);
                acc[fr][fc] = __builtin_amdgcn_mfma_f32_16x16x32_bf16(al[fr], bh[fc], acc[fr][fc], 0, 0, 0);
            }
    }

    // ---- epilogue: C/D layout col = lane&15, row = (lane>>4)*4 + reg ----
    int rq = (lane >> 4) << 2;
#pragma unroll
    for (int fr = 0; fr < 2; ++fr) {
#pragma unroll
        for (int fc = 0; fc < 2; ++fc) {
            int cg = (ntile << 6) + (wn << 5) + (fc << 4) + l15;
#pragma unroll
            for (int rg = 0; rg < 4; ++rg) {
                int r = rowBase + (wm << 5) + (fr << 4) + rq + rg;
                if (r < M) {
                    float v = acc[fr][fc][rg];
                    if (scale) v *= scale[r];
                    if (bias) v += bias[cg];
                    size_t oo = (size_t)r * 128 + cg;
                    if (accumulate) v += out[oo];
                    out[oo] = v;
                }
            }
        }
    }
}

// ---------------- Aggregation: one wave per dst node, 2 edges/iteration ----------------
// h is pre-scaled: h'[v] = (x@W)[v] * dinv[v].
// xout[v] = relu(dinv[v] * (sum_{e:dst=v} h'[col[e]] + h'[v]) + bias)

__global__ __launch_bounds__(256) void k_agg(
    const float* __restrict__ h, const int* __restrict__ col,
    const int* __restrict__ offs, const float* __restrict__ dinv,
    const float* __restrict__ bias, float* __restrict__ xout, int n) {
    int lane = threadIdx.x & 63;
    int half = lane >> 5;
    int li = lane & 31;
    int v = (blockIdx.x << 2) + (threadIdx.x >> 6);
    if (v >= n) return;
    int beg = offs[v], end = offs[v + 1];
    float dv = dinv[v];
    float ax = 0.f, ay = 0.f, az = 0.f, aw = 0.f;
    if (half == 0) {   // self-loop contribution, counted once
        float4 hv = *(const float4*)&h[(size_t)v * 128 + (li << 2)];
        ax = hv.x; ay = hv.y; az = hv.z; aw = hv.w;
    }
    int e = beg + half;            // half 0: even offsets, half 1: odd offsets
    for (; e + 2 < end; e += 4) {
        int sA = col[e], sB = col[e + 2];
        float4 a = *(const float4*)&h[(size_t)sA * 128 + (li << 2)];
        float4 b = *(const float4*)&h[(size_t)sB * 128 + (li << 2)];
        ax += a.x + b.x; ay += a.y + b.y; az += a.z + b.z; aw += a.w + b.w;
    }
    if (e < end) {
        int sA = col[e];
        float4 a = *(const float4*)&h[(size_t)sA * 128 + (li << 2)];
        ax += a.x; ay += a.y; az += a.z; aw += a.w;
    }
    ax += __shfl_xor(ax, 32);
    ay += __shfl_xor(ay, 32);
    az += __shfl_xor(az, 32);
    aw += __shfl_xor(aw, 32);
    if (half == 0) {
        float4 bv = *(const float4*)&bias[li << 2];
        float4 o;
        o.x = fmaxf(fmaf(ax, dv, bv.x), 0.f);
        o.y = fmaxf(fmaf(ay, dv, bv.y), 0.f);
        o.z = fmaxf(fmaf(az, dv, bv.z), 0.f);
        o.w = fmaxf(fmaf(aw, dv, bv.w), 0.f);
        *(float4*)&xout[(size_t)v * 128 + (li << 2)] = o;
    }
}

// ---------------- Final dot ----------------

__global__ __launch_bounds__(256) void k_dot(
    const float* __restrict__ P, const float* __restrict__ Q,
    float* __restrict__ out, int B) {
    int lane = threadIdx.x & 63;
    int b = (blockIdx.x << 2) + (threadIdx.x >> 6);
    if (b >= B) return;
    float2 p = *(const float2*)&P[(size_t)b * 128 + lane * 2];
    float2 q = *(const float2*)&Q[(size_t)b * 128 + lane * 2];
    float s = p.x * q.x + p.y * q.y;
#pragma unroll
    for (int off = 32; off; off >>= 1) s += __shfl_down(s, off);
    if (lane == 0) out[b] = s;
}

// ---------------- launch ----------------

extern "C" void kernel_launch(void* const* d_in, const int* in_sizes, int n_in,
                              void* d_out, int out_size, void* d_ws, size_t ws_size,
                              hipStream_t stream) {
    const float* x    = (const float*)d_in[0];
    const int*   edge = (const int*)d_in[1];
    const int*   sidx = (const int*)d_in[2];
    const int*   tidx = (const int*)d_in[3];
    const float* Wc0  = (const float*)d_in[4];
    const float* bc0  = (const float*)d_in[5];
    const float* Wc1  = (const float*)d_in[6];
    const float* bc1  = (const float*)d_in[7];
    const float* Wc2  = (const float*)d_in[8];
    const float* bc2  = (const float*)d_in[9];
    const float* Ww   = (const float*)d_in[10];
    const float* bw   = (const float*)d_in[11];
    const float* Wp   = (const float*)d_in[12];
    const float* bp   = (const float*)d_in[13];
    float* out = (float*)d_out;

    char* base = (char*)d_ws;
    size_t off = 0;
    auto alloc = [&](size_t bytes) -> char* {
        char* p = base + off;
        off = (off + bytes + 255) & ~(size_t)255;
        return p;
    };
    const size_t FSZ = (size_t)N_NODES * HID * sizeof(float);
    float* bufA   = (float*)alloc(FSZ);
    float* bufB   = (float*)alloc(FSZ);
    float* bufH   = (float*)alloc(FSZ);
    float* Pm     = (float*)alloc((size_t)BATCH * HID * sizeof(float));
    float* Qm     = (float*)alloc((size_t)BATCH * HID * sizeof(float));
    int*   counts = (int*)alloc((size_t)N_NODES * sizeof(int));
    int*   offsets= (int*)alloc((size_t)(N_NODES + 1) * sizeof(int));
    int*   cursor = (int*)alloc((size_t)N_NODES * sizeof(int));
    int*   colArr = (int*)alloc((size_t)N_EDGES * sizeof(int));
    float* dinv   = (float*)alloc((size_t)N_NODES * sizeof(float));
    int*   chunkSum  = (int*)alloc(512 * sizeof(int));
    int*   chunkBase = (int*)alloc(512 * sizeof(int));
    short* wtH = (short*)alloc((size_t)9 * 16384 * sizeof(short));
    short* wtL = (short*)alloc((size_t)9 * 16384 * sizeof(short));
    (void)ws_size; (void)in_sizes; (void)n_in; (void)out_size;

    // ---- CSR build ----
    hipMemsetAsync(counts, 0, (size_t)N_NODES * sizeof(int), stream);
    {
        int g = (N_EDGES + 255) / 256;
        k_hist<<<g, 256, 0, stream>>>(edge + N_EDGES, counts, N_EDGES);
    }
    k_scan1<<<NCHUNKS, 256, 0, stream>>>(counts, chunkSum, N_NODES);
    k_scan2<<<1, 128, 0, stream>>>(chunkSum, chunkBase, offsets, NCHUNKS, N_NODES);
    k_scan3<<<NCHUNKS, 256, 0, stream>>>(counts, chunkBase, offsets, N_NODES);
    k_dinv<<<(N_NODES + 255) / 256, 256, 0, stream>>>(counts, dinv, N_NODES);
    hipMemcpyAsync(cursor, offsets, (size_t)N_NODES * sizeof(int),
                   hipMemcpyDeviceToDevice, stream);
    {
        int g = (N_EDGES + 255) / 256;
        k_scatter<<<g, 256, 0, stream>>>(edge, cursor, colArr, N_EDGES);
    }

    // ---- weight prep ----
    k_prepW<<<9, 256, 0, stream>>>(Wc0, Wc1, Wc2, Wp, Ww, wtH, wtL);

    const int gridN = ((N_NODES + 63) / 64) * 2;   // 3126
    const int gridB = (BATCH / 64) * 2;            // 512
    const int aggGrid = (N_NODES + 3) / 4;
    const int dotGrid = (BATCH + 3) / 4;
#define WT(c) (wtH + (c) * 16384), (wtL + (c) * 16384)

    // ---- layer 1 ----
    k_mgemm<<<gridN, 256, 0, stream>>>(x, WT(0), bufH, nullptr, nullptr, dinv, N_NODES, 0);
    k_agg<<<aggGrid, 256, 0, stream>>>(bufH, colArr, offsets, dinv, bc0, bufA, N_NODES);
    k_mgemm<<<gridB, 256, 0, stream>>>(bufA, WT(3), Pm, sidx, bp, nullptr, BATCH, 0);
    k_mgemm<<<gridB, 256, 0, stream>>>(bufA, WT(6), Qm, tidx, bw, nullptr, BATCH, 0);

    // ---- layer 2 ----
    k_mgemm<<<gridN, 256, 0, stream>>>(bufA, WT(1), bufH, nullptr, nullptr, dinv, N_NODES, 0);
    k_agg<<<aggGrid, 256, 0, stream>>>(bufH, colArr, offsets, dinv, bc1, bufB, N_NODES);
    k_mgemm<<<gridB, 256, 0, stream>>>(bufB, WT(4), Pm, sidx, nullptr, nullptr, BATCH, 1);
    k_mgemm<<<gridB, 256, 0, stream>>>(bufB, WT(7), Qm, tidx, nullptr, nullptr, BATCH, 1);

    // ---- layer 3 ----
    k_mgemm<<<gridN, 256, 0, stream>>>(bufB, WT(2), bufH, nullptr, nullptr, dinv, N_NODES, 0);
    k_agg<<<aggGrid, 256, 0, stream>>>(bufH, colArr, offsets, dinv, bc2, bufA, N_NODES);
    k_mgemm<<<gridB, 256, 0, stream>>>(bufA, WT(5), Pm, sidx, nullptr, nullptr, BATCH, 1);
    k_mgemm<<<gridB, 256, 0, stream>>>(bufA, WT(8), Qm, tidx, nullptr, nullptr, BATCH, 1);

    // ---- score ----
    k_dot<<<dotGrid, 256, 0, stream>>>(Pm, Qm, out, BATCH);
}

// Round 3
// 690.597 us; speedup vs baseline: 1.2834x; 1.2095x over previous
//
#include <hip/hip_runtime.h>
#include <hip/hip_bf16.h>

#define N_NODES 100000
#define N_EDGES 1600000
#define BATCH   16384
#define HID     128

#define SHIFT 9
#define BSZ   512                       // nodes per bucket
#define NB    196                       // ceil(100000/512)
#define EPB   8192                      // edges per passA block

typedef __attribute__((ext_vector_type(8))) short bf16x8;
typedef __attribute__((ext_vector_type(4))) float fx4;

__device__ inline short f2bf(float f) {
    unsigned u = __builtin_bit_cast(unsigned, f);
    unsigned r = (u + 0x7FFF + ((u >> 16) & 1)) >> 16;
    return (short)r;
}
__device__ inline float bf2f(short s) {
    unsigned u = ((unsigned)(unsigned short)s) << 16;
    return __builtin_bit_cast(float, u);
}

// ---------------- CSR build: bucketed two-pass ----------------

__global__ __launch_bounds__(256) void k_bhist(const int* __restrict__ dst,
                                               int* __restrict__ bcnt, int E) {
    __shared__ int lh[NB];
    int t = threadIdx.x;
    for (int j = t; j < NB; j += 256) lh[j] = 0;
    __syncthreads();
    int base = blockIdx.x * 4096;
    int n = min(4096, E - base);
    for (int i = t; i < n; i += 256) atomicAdd(&lh[dst[base + i] >> SHIFT], 1);
    __syncthreads();
    for (int j = t; j < NB; j += 256)
        if (lh[j]) atomicAdd(&bcnt[j], lh[j]);
}

__global__ void k_bscan(const int* __restrict__ bcnt, int* __restrict__ bbase,
                        int* __restrict__ bcur, int* __restrict__ offsets) {
    __shared__ int sh[256];
    int t = threadIdx.x;
    int c = (t < NB) ? bcnt[t] : 0;
    sh[t] = c;
    __syncthreads();
    for (int off = 1; off < 256; off <<= 1) {
        int v = 0;
        if (t >= off) v = sh[t - off];
        __syncthreads();
        if (t >= off) sh[t] += v;
        __syncthreads();
    }
    int incl = sh[t];
    int excl = incl - c;
    if (t < NB) { bbase[t] = excl; bcur[t] = excl; }
    if (t == NB - 1) { bbase[NB] = incl; offsets[N_NODES] = incl; }
}

// partition edges into bucket-contiguous tmp[], packed src|dstLow<<17
__global__ __launch_bounds__(256) void k_passA(
    const int* __restrict__ edge, int* __restrict__ bcur,
    unsigned* __restrict__ tmp, int E) {
    __shared__ unsigned staged[EPB];
    __shared__ unsigned char bkt[EPB];
    __shared__ int lh[NB], lstart[NB], gbase[NB], lcur[NB];
    int t = threadIdx.x;
    int base = blockIdx.x * EPB;
    int n = min(EPB, E - base);
    for (int j = t; j < NB; j += 256) lh[j] = 0;
    __syncthreads();
    for (int i = t; i < n; i += 256)
        atomicAdd(&lh[edge[E + base + i] >> SHIFT], 1);
    __syncthreads();
    if (t == 0) {
        int run = 0;
        for (int b = 0; b < NB; ++b) { lstart[b] = run; run += lh[b]; }
    }
    __syncthreads();
    if (t < NB) {
        gbase[t] = atomicAdd(&bcur[t], lh[t]);
        lcur[t] = lstart[t];
    }
    __syncthreads();
    for (int i = t; i < n; i += 256) {
        int s = edge[base + i];
        int d = edge[E + base + i];
        int b = d >> SHIFT;
        unsigned p = (unsigned)s | ((unsigned)(d & (BSZ - 1)) << 17);
        int pos = atomicAdd(&lcur[b], 1);
        staged[pos] = p;
        bkt[pos] = (unsigned char)b;
    }
    __syncthreads();
    for (int i = t; i < n; i += 256) {
        int b = bkt[i];
        tmp[gbase[b] + (i - lstart[b])] = staged[i];
    }
}

// per bucket: per-node counts (LDS hist) -> scan -> offsets+dinv -> scatter col
__global__ __launch_bounds__(256) void k_passB(
    const unsigned* __restrict__ tmp, const int* __restrict__ bbase,
    int* __restrict__ offsets, float* __restrict__ dinv,
    int* __restrict__ col) {
    __shared__ int lh[BSZ];
    __shared__ int lsum[256];
    int b = blockIdx.x, t = threadIdx.x;
    int begin = bbase[b], end = bbase[b + 1];
    lh[t] = 0; lh[t + 256] = 0;
    __syncthreads();
    for (int i = begin + t; i < end; i += 256)
        atomicAdd(&lh[tmp[i] >> 17], 1);
    __syncthreads();
    int c0 = lh[2 * t], c1 = lh[2 * t + 1];
    int tsum = c0 + c1;
    lsum[t] = tsum;
    __syncthreads();
    for (int off = 1; off < 256; off <<= 1) {
        int v = 0;
        if (t >= off) v = lsum[t - off];
        __syncthreads();
        if (t >= off) lsum[t] += v;
        __syncthreads();
    }
    int texcl = lsum[t] - tsum;
    int node0 = (b << SHIFT) + 2 * t;
    if (node0 < N_NODES) {
        offsets[node0] = begin + texcl;
        dinv[node0] = rsqrtf((float)c0 + 1.f);
    }
    if (node0 + 1 < N_NODES) {
        offsets[node0 + 1] = begin + texcl + c0;
        dinv[node0 + 1] = rsqrtf((float)c1 + 1.f);
    }
    __syncthreads();
    lh[2 * t] = texcl;
    lh[2 * t + 1] = texcl + c0;
    __syncthreads();
    for (int i = begin + t; i < end; i += 1024) {
        int i1 = i + 256, i2 = i + 512, i3 = i + 768;
        unsigned p0 = tmp[i];
        unsigned p1 = (i1 < end) ? tmp[i1] : 0u;
        unsigned p2 = (i2 < end) ? tmp[i2] : 0u;
        unsigned p3 = (i3 < end) ? tmp[i3] : 0u;
        int pos0 = begin + atomicAdd(&lh[p0 >> 17], 1);
        col[pos0] = (int)(p0 & 0x1FFFFu);
        if (i1 < end) { int q = begin + atomicAdd(&lh[p1 >> 17], 1); col[q] = (int)(p1 & 0x1FFFFu); }
        if (i2 < end) { int q = begin + atomicAdd(&lh[p2 >> 17], 1); col[q] = (int)(p2 & 0x1FFFFu); }
        if (i3 < end) { int q = begin + atomicAdd(&lh[p3 >> 17], 1); col[q] = (int)(p3 & 0x1FFFFu); }
    }
}

// ---------------- weight prep: split fp32 W[k][n] -> bf16 hi/lo, transposed ----------------

__global__ void k_prepW(const float* __restrict__ Wc0, const float* __restrict__ Wc1,
                        const float* __restrict__ Wc2, const float* __restrict__ Wp,
                        const float* __restrict__ Ww,
                        short* __restrict__ outH, short* __restrict__ outL) {
    int c = blockIdx.x;
    const float* src;
    int koff = 0;
    if (c == 0) src = Wc0;
    else if (c == 1) src = Wc1;
    else if (c == 2) src = Wc2;
    else if (c < 6) { src = Wp; koff = (c - 3) * 128; }
    else { src = Ww; koff = (c - 6) * 128; }
    short* dh = outH + c * 16384;
    short* dl = outL + c * 16384;
    for (int i = threadIdx.x; i < 16384; i += 256) {
        int k = i >> 7, n = i & 127;
        float v = src[(size_t)(koff + k) * 128 + n];
        short h = f2bf(v);
        short l = f2bf(v - bf2f(h));
        dh[n * 128 + k] = h;
        dl[n * 128 + k] = l;
    }
}

// ---------------- split-bf16 MFMA GEMM (unchanged) ----------------

__global__ __launch_bounds__(256) void k_mgemm(
    const float* __restrict__ A, const short* __restrict__ WTh,
    const short* __restrict__ WTl, float* __restrict__ out,
    const int* __restrict__ gidx, const float* __restrict__ bias,
    const float* __restrict__ scale, int M, int accumulate) {
    __shared__ short Ah[64 * 128];
    __shared__ short Al[64 * 128];
    __shared__ short Bh[64 * 128];
    __shared__ short Bl[64 * 128];

    int t = threadIdx.x;
    int mtile = blockIdx.x >> 1, ntile = blockIdx.x & 1;
    int rowBase = mtile << 6;

#pragma unroll
    for (int j = 0; j < 8; ++j) {
        int row = (t >> 5) + (j << 3);
        int colf = (t & 31) << 2;
        int gr = rowBase + row;
        float4 v = make_float4(0.f, 0.f, 0.f, 0.f);
        if (gr < M) {
            long long ar = gidx ? (long long)gidx[gr] : (long long)gr;
            v = *(const float4*)&A[(size_t)ar * 128 + colf];
        }
        short4 hi, lo;
        hi.x = f2bf(v.x); lo.x = f2bf(v.x - bf2f(hi.x));
        hi.y = f2bf(v.y); lo.y = f2bf(v.y - bf2f(hi.y));
        hi.z = f2bf(v.z); lo.z = f2bf(v.z - bf2f(hi.z));
        hi.w = f2bf(v.w); lo.w = f2bf(v.w - bf2f(hi.w));
        unsigned off = (unsigned)(row << 8) + (((unsigned)(colf << 1)) ^ ((unsigned)((row & 7) << 4)));
        *(short4*)((char*)Ah + off) = hi;
        *(short4*)((char*)Al + off) = lo;
    }
#pragma unroll
    for (int j = 0; j < 4; ++j) {
        int c = (t >> 4) + (j << 4);
        int k8 = (t & 15) << 3;
        size_t goff = ((size_t)((ntile << 6) + c) << 7) + k8;
        bf16x8 wh = *(const bf16x8*)&WTh[goff];
        bf16x8 wl = *(const bf16x8*)&WTl[goff];
        unsigned off = (unsigned)(c << 8) + (((unsigned)(k8 << 1)) ^ ((unsigned)((c & 7) << 4)));
        *(bf16x8*)((char*)Bh + off) = wh;
        *(bf16x8*)((char*)Bl + off) = wl;
    }
    __syncthreads();

    int lane = t & 63;
    int wave = t >> 6;
    int wm = wave >> 1, wn = wave & 1;
    int l15 = lane & 15;
    int kq = (lane >> 4) << 4;

    fx4 acc[2][2];
#pragma unroll
    for (int i = 0; i < 2; ++i)
#pragma unroll
        for (int j = 0; j < 2; ++j) {
            acc[i][j][0] = 0.f; acc[i][j][1] = 0.f;
            acc[i][j][2] = 0.f; acc[i][j][3] = 0.f;
        }

    int ar0 = (wm << 5) + l15;
    int bc0 = (wn << 5) + l15;

#pragma unroll
    for (int k = 0; k < 4; ++k) {
        int kb = (k << 6) + kq;
        bf16x8 ah[2], al[2], bh[2], bl[2];
#pragma unroll
        for (int fr = 0; fr < 2; ++fr) {
            int r = ar0 + (fr << 4);
            unsigned off = (unsigned)(r << 8) + ((unsigned)kb ^ ((unsigned)((r & 7) << 4)));
            ah[fr] = *(const bf16x8*)((const char*)Ah + off);
            al[fr] = *(const bf16x8*)((const char*)Al + off);
        }
#pragma unroll
        for (int fc = 0; fc < 2; ++fc) {
            int c = bc0 + (fc << 4);
            unsigned off = (unsigned)(c << 8) + ((unsigned)kb ^ ((unsigned)((c & 7) << 4)));
            bh[fc] = *(const bf16x8*)((const char*)Bh + off);
            bl[fc] = *(const bf16x8*)((const char*)Bl + off);
        }
#pragma unroll
        for (int fr = 0; fr < 2; ++fr)
#pragma unroll
            for (int fc = 0; fc < 2; ++fc) {
                acc[fr][fc] = __builtin_amdgcn_mfma_f32_16x16x32_bf16(ah[fr], bh[fc], acc[fr][fc], 0, 0, 0);
                acc[fr][fc] = __builtin_amdgcn_mfma_f32_16x16x32_bf16(ah[fr], bl[fc], acc[fr][fc], 0, 0, 0);
                acc[fr][fc] = __builtin_amdgcn_mfma_f32_16x16x32_bf16(al[fr], bh[fc], acc[fr][fc], 0, 0, 0);
            }
    }

    int rq = (lane >> 4) << 2;
#pragma unroll
    for (int fr = 0; fr < 2; ++fr) {
#pragma unroll
        for (int fc = 0; fc < 2; ++fc) {
            int cg = (ntile << 6) + (wn << 5) + (fc << 4) + l15;
#pragma unroll
            for (int rg = 0; rg < 4; ++rg) {
                int r = rowBase + (wm << 5) + (fr << 4) + rq + rg;
                if (r < M) {
                    float v = acc[fr][fc][rg];
                    if (scale) v *= scale[r];
                    if (bias) v += bias[cg];
                    size_t oo = (size_t)r * 128 + cg;
                    if (accumulate) v += out[oo];
                    out[oo] = v;
                }
            }
        }
    }
}

// ---------------- Aggregation: one wave per dst node, 4 lane-groups x 16 lanes ----------------
// h pre-scaled by dinv[row]; xout[v] = relu(dinv[v]*(sum h'[col[e]] + h'[v]) + bias)

__global__ __launch_bounds__(256) void k_agg(
    const float* __restrict__ h, const int* __restrict__ col,
    const int* __restrict__ offs, const float* __restrict__ dinv,
    const float* __restrict__ bias, float* __restrict__ xout, int n) {
    int lane = threadIdx.x & 63;
    int g = lane >> 4;          // 4 groups
    int li = lane & 15;         // 16 lanes, 32B each
    int v = (blockIdx.x << 2) + (threadIdx.x >> 6);
    if (v >= n) return;
    int beg = offs[v], end = offs[v + 1];
    float dv = dinv[v];
    float4 a0 = make_float4(0.f, 0.f, 0.f, 0.f);
    float4 a1 = make_float4(0.f, 0.f, 0.f, 0.f);
    const float* hv = &h[(size_t)v * 128 + (li << 3)];
    if (g == 0) {
        a0 = *(const float4*)hv;
        a1 = *(const float4*)(hv + 4);
    }
    int e = beg + g;
    for (; e + 4 < end; e += 8) {
        int sA = col[e], sB = col[e + 4];
        const float* pA = &h[(size_t)sA * 128 + (li << 3)];
        const float* pB = &h[(size_t)sB * 128 + (li << 3)];
        float4 xA0 = *(const float4*)pA;
        float4 xA1 = *(const float4*)(pA + 4);
        float4 xB0 = *(const float4*)pB;
        float4 xB1 = *(const float4*)(pB + 4);
        a0.x += xA0.x + xB0.x; a0.y += xA0.y + xB0.y;
        a0.z += xA0.z + xB0.z; a0.w += xA0.w + xB0.w;
        a1.x += xA1.x + xB1.x; a1.y += xA1.y + xB1.y;
        a1.z += xA1.z + xB1.z; a1.w += xA1.w + xB1.w;
    }
    if (e < end) {
        const float* pA = &h[(size_t)col[e] * 128 + (li << 3)];
        float4 xA0 = *(const float4*)pA;
        float4 xA1 = *(const float4*)(pA + 4);
        a0.x += xA0.x; a0.y += xA0.y; a0.z += xA0.z; a0.w += xA0.w;
        a1.x += xA1.x; a1.y += xA1.y; a1.z += xA1.z; a1.w += xA1.w;
    }
#pragma unroll
    for (int off = 16; off <= 32; off <<= 1) {
        a0.x += __shfl_xor(a0.x, off); a0.y += __shfl_xor(a0.y, off);
        a0.z += __shfl_xor(a0.z, off); a0.w += __shfl_xor(a0.w, off);
        a1.x += __shfl_xor(a1.x, off); a1.y += __shfl_xor(a1.y, off);
        a1.z += __shfl_xor(a1.z, off); a1.w += __shfl_xor(a1.w, off);
    }
    if (g == 0) {
        float4 b0 = *(const float4*)&bias[li << 3];
        float4 b1 = *(const float4*)&bias[(li << 3) + 4];
        float4 o0, o1;
        o0.x = fmaxf(fmaf(a0.x, dv, b0.x), 0.f);
        o0.y = fmaxf(fmaf(a0.y, dv, b0.y), 0.f);
        o0.z = fmaxf(fmaf(a0.z, dv, b0.z), 0.f);
        o0.w = fmaxf(fmaf(a0.w, dv, b0.w), 0.f);
        o1.x = fmaxf(fmaf(a1.x, dv, b1.x), 0.f);
        o1.y = fmaxf(fmaf(a1.y, dv, b1.y), 0.f);
        o1.z = fmaxf(fmaf(a1.z, dv, b1.z), 0.f);
        o1.w = fmaxf(fmaf(a1.w, dv, b1.w), 0.f);
        float* op = &xout[(size_t)v * 128 + (li << 3)];
        *(float4*)op = o0;
        *(float4*)(op + 4) = o1;
    }
}

// ---------------- Final dot ----------------

__global__ __launch_bounds__(256) void k_dot(
    const float* __restrict__ P, const float* __restrict__ Q,
    float* __restrict__ out, int B) {
    int lane = threadIdx.x & 63;
    int b = (blockIdx.x << 2) + (threadIdx.x >> 6);
    if (b >= B) return;
    float2 p = *(const float2*)&P[(size_t)b * 128 + lane * 2];
    float2 q = *(const float2*)&Q[(size_t)b * 128 + lane * 2];
    float s = p.x * q.x + p.y * q.y;
#pragma unroll
    for (int off = 32; off; off >>= 1) s += __shfl_down(s, off);
    if (lane == 0) out[b] = s;
}

// ---------------- launch ----------------

extern "C" void kernel_launch(void* const* d_in, const int* in_sizes, int n_in,
                              void* d_out, int out_size, void* d_ws, size_t ws_size,
                              hipStream_t stream) {
    const float* x    = (const float*)d_in[0];
    const int*   edge = (const int*)d_in[1];
    const int*   sidx = (const int*)d_in[2];
    const int*   tidx = (const int*)d_in[3];
    const float* Wc0  = (const float*)d_in[4];
    const float* bc0  = (const float*)d_in[5];
    const float* Wc1  = (const float*)d_in[6];
    const float* bc1  = (const float*)d_in[7];
    const float* Wc2  = (const float*)d_in[8];
    const float* bc2  = (const float*)d_in[9];
    const float* Ww   = (const float*)d_in[10];
    const float* bw   = (const float*)d_in[11];
    const float* Wp   = (const float*)d_in[12];
    const float* bp   = (const float*)d_in[13];
    float* out = (float*)d_out;

    char* base = (char*)d_ws;
    size_t off = 0;
    auto alloc = [&](size_t bytes) -> char* {
        char* p = base + off;
        off = (off + bytes + 255) & ~(size_t)255;
        return p;
    };
    const size_t FSZ = (size_t)N_NODES * HID * sizeof(float);
    float* bufA    = (float*)alloc(FSZ);
    float* bufB    = (float*)alloc(FSZ);
    float* bufH    = (float*)alloc(FSZ);
    float* Pm      = (float*)alloc((size_t)BATCH * HID * sizeof(float));
    float* Qm      = (float*)alloc((size_t)BATCH * HID * sizeof(float));
    int*   offsets = (int*)alloc((size_t)(N_NODES + 1) * sizeof(int));
    int*   colArr  = (int*)alloc((size_t)N_EDGES * sizeof(int));
    unsigned* tmp  = (unsigned*)alloc((size_t)N_EDGES * sizeof(unsigned));
    float* dinv    = (float*)alloc((size_t)N_NODES * sizeof(float));
    int*   bcnt    = (int*)alloc(256 * sizeof(int));
    int*   bbase   = (int*)alloc(256 * sizeof(int));
    int*   bcur    = (int*)alloc(256 * sizeof(int));
    short* wtH     = (short*)alloc((size_t)9 * 16384 * sizeof(short));
    short* wtL     = (short*)alloc((size_t)9 * 16384 * sizeof(short));
    (void)ws_size; (void)in_sizes; (void)n_in; (void)out_size;

    // ---- CSR build (bucketed) ----
    hipMemsetAsync(bcnt, 0, NB * sizeof(int), stream);
    k_bhist<<<(N_EDGES + 4095) / 4096, 256, 0, stream>>>(edge + N_EDGES, bcnt, N_EDGES);
    k_bscan<<<1, 256, 0, stream>>>(bcnt, bbase, bcur, offsets);
    k_passA<<<(N_EDGES + EPB - 1) / EPB, 256, 0, stream>>>(edge, bcur, tmp, N_EDGES);
    k_passB<<<NB, 256, 0, stream>>>(tmp, bbase, offsets, dinv, colArr);

    // ---- weight prep ----
    k_prepW<<<9, 256, 0, stream>>>(Wc0, Wc1, Wc2, Wp, Ww, wtH, wtL);

    const int gridN = ((N_NODES + 63) / 64) * 2;
    const int gridB = (BATCH / 64) * 2;
    const int aggGrid = (N_NODES + 3) / 4;
    const int dotGrid = (BATCH + 3) / 4;
#define WT(c) (wtH + (c) * 16384), (wtL + (c) * 16384)

    // ---- layer 1 ----
    k_mgemm<<<gridN, 256, 0, stream>>>(x, WT(0), bufH, nullptr, nullptr, dinv, N_NODES, 0);
    k_agg<<<aggGrid, 256, 0, stream>>>(bufH, colArr, offsets, dinv, bc0, bufA, N_NODES);
    k_mgemm<<<gridB, 256, 0, stream>>>(bufA, WT(3), Pm, sidx, bp, nullptr, BATCH, 0);
    k_mgemm<<<gridB, 256, 0, stream>>>(bufA, WT(6), Qm, tidx, bw, nullptr, BATCH, 0);

    // ---- layer 2 ----
    k_mgemm<<<gridN, 256, 0, stream>>>(bufA, WT(1), bufH, nullptr, nullptr, dinv, N_NODES, 0);
    k_agg<<<aggGrid, 256, 0, stream>>>(bufH, colArr, offsets, dinv, bc1, bufB, N_NODES);
    k_mgemm<<<gridB, 256, 0, stream>>>(bufB, WT(4), Pm, sidx, nullptr, nullptr, BATCH, 1);
    k_mgemm<<<gridB, 256, 0, stream>>>(bufB, WT(7), Qm, tidx, nullptr, nullptr, BATCH, 1);

    // ---- layer 3 ----
    k_mgemm<<<gridN, 256, 0, stream>>>(bufB, WT(2), bufH, nullptr, nullptr, dinv, N_NODES, 0);
    k_agg<<<aggGrid, 256, 0, stream>>>(bufH, colArr, offsets, dinv, bc2, bufA, N_NODES);
    k_mgemm<<<gridB, 256, 0, stream>>>(bufA, WT(5), Pm, sidx, nullptr, nullptr, BATCH, 1);
    k_mgemm<<<gridB, 256, 0, stream>>>(bufA, WT(8), Qm, tidx, nullptr, nullptr, BATCH, 1);

    // ---- score ----
    k_dot<<<dotGrid, 256, 0, stream>>>(Pm, Qm, out, BATCH);
}

// Round 4
// 534.061 us; speedup vs baseline: 1.6595x; 1.2931x over previous
//
#include <hip/hip_runtime.h>
#include <hip/hip_bf16.h>

#define N_NODES 100000
#define N_EDGES 1600000
#define BATCH   16384
#define HID     128

#define SHIFT 9
#define BSZ   512
#define NB    196
#define EPB   8192

typedef __attribute__((ext_vector_type(8))) short bf16x8;
typedef __attribute__((ext_vector_type(4))) float fx4;

__device__ inline short f2bf(float f) {
    unsigned u = __builtin_bit_cast(unsigned, f);
    unsigned r = (u + 0x7FFF + ((u >> 16) & 1)) >> 16;
    return (short)r;
}
__device__ inline float bf2f(short s) {
    unsigned u = ((unsigned)(unsigned short)s) << 16;
    return __builtin_bit_cast(float, u);
}

// ---------------- CSR build: bucketed two-pass ----------------

__global__ __launch_bounds__(256) void k_bhist(const int* __restrict__ dst,
                                               int* __restrict__ bcnt, int E) {
    __shared__ int lh[NB];
    int t = threadIdx.x;
    for (int j = t; j < NB; j += 256) lh[j] = 0;
    __syncthreads();
    int base = blockIdx.x * 4096;
    int n = min(4096, E - base);
    for (int i = t; i < n; i += 256) atomicAdd(&lh[dst[base + i] >> SHIFT], 1);
    __syncthreads();
    for (int j = t; j < NB; j += 256)
        if (lh[j]) atomicAdd(&bcnt[j], lh[j]);
}

__global__ void k_bscan(const int* __restrict__ bcnt, int* __restrict__ bbase,
                        int* __restrict__ bcur, int* __restrict__ offsets) {
    __shared__ int sh[256];
    int t = threadIdx.x;
    int c = (t < NB) ? bcnt[t] : 0;
    sh[t] = c;
    __syncthreads();
    for (int off = 1; off < 256; off <<= 1) {
        int v = 0;
        if (t >= off) v = sh[t - off];
        __syncthreads();
        if (t >= off) sh[t] += v;
        __syncthreads();
    }
    int incl = sh[t];
    int excl = incl - c;
    if (t < NB) { bbase[t] = excl; bcur[t] = excl; }
    if (t == NB - 1) { bbase[NB] = incl; offsets[N_NODES] = incl; }
}

__global__ __launch_bounds__(256) void k_passA(
    const int* __restrict__ edge, int* __restrict__ bcur,
    unsigned* __restrict__ tmp, int E) {
    __shared__ unsigned staged[EPB];
    __shared__ unsigned char bkt[EPB];
    __shared__ int lh[NB], lstart[NB], gbase[NB], lcur[NB];
    int t = threadIdx.x;
    int base = blockIdx.x * EPB;
    int n = min(EPB, E - base);
    for (int j = t; j < NB; j += 256) lh[j] = 0;
    __syncthreads();
    for (int i = t; i < n; i += 256)
        atomicAdd(&lh[edge[E + base + i] >> SHIFT], 1);
    __syncthreads();
    if (t == 0) {
        int run = 0;
        for (int b = 0; b < NB; ++b) { lstart[b] = run; run += lh[b]; }
    }
    __syncthreads();
    if (t < NB) {
        gbase[t] = atomicAdd(&bcur[t], lh[t]);
        lcur[t] = lstart[t];
    }
    __syncthreads();
    for (int i = t; i < n; i += 256) {
        int s = edge[base + i];
        int d = edge[E + base + i];
        int b = d >> SHIFT;
        unsigned p = (unsigned)s | ((unsigned)(d & (BSZ - 1)) << 17);
        int pos = atomicAdd(&lcur[b], 1);
        staged[pos] = p;
        bkt[pos] = (unsigned char)b;
    }
    __syncthreads();
    for (int i = t; i < n; i += 256) {
        int b = bkt[i];
        tmp[gbase[b] + (i - lstart[b])] = staged[i];
    }
}

__global__ __launch_bounds__(256) void k_passB(
    const unsigned* __restrict__ tmp, const int* __restrict__ bbase,
    int* __restrict__ offsets, float* __restrict__ dinv,
    int* __restrict__ col) {
    __shared__ int lh[BSZ];
    __shared__ int lsum[256];
    int b = blockIdx.x, t = threadIdx.x;
    int begin = bbase[b], end = bbase[b + 1];
    lh[t] = 0; lh[t + 256] = 0;
    __syncthreads();
    for (int i = begin + t; i < end; i += 256)
        atomicAdd(&lh[tmp[i] >> 17], 1);
    __syncthreads();
    int c0 = lh[2 * t], c1 = lh[2 * t + 1];
    int tsum = c0 + c1;
    lsum[t] = tsum;
    __syncthreads();
    for (int off = 1; off < 256; off <<= 1) {
        int v = 0;
        if (t >= off) v = lsum[t - off];
        __syncthreads();
        if (t >= off) lsum[t] += v;
        __syncthreads();
    }
    int texcl = lsum[t] - tsum;
    int node0 = (b << SHIFT) + 2 * t;
    if (node0 < N_NODES) {
        offsets[node0] = begin + texcl;
        dinv[node0] = rsqrtf((float)c0 + 1.f);
    }
    if (node0 + 1 < N_NODES) {
        offsets[node0 + 1] = begin + texcl + c0;
        dinv[node0 + 1] = rsqrtf((float)c1 + 1.f);
    }
    __syncthreads();
    lh[2 * t] = texcl;
    lh[2 * t + 1] = texcl + c0;
    __syncthreads();
    for (int i = begin + t; i < end; i += 1024) {
        int i1 = i + 256, i2 = i + 512, i3 = i + 768;
        unsigned p0 = tmp[i];
        unsigned p1 = (i1 < end) ? tmp[i1] : 0u;
        unsigned p2 = (i2 < end) ? tmp[i2] : 0u;
        unsigned p3 = (i3 < end) ? tmp[i3] : 0u;
        int pos0 = begin + atomicAdd(&lh[p0 >> 17], 1);
        col[pos0] = (int)(p0 & 0x1FFFFu);
        if (i1 < end) { int q = begin + atomicAdd(&lh[p1 >> 17], 1); col[q] = (int)(p1 & 0x1FFFFu); }
        if (i2 < end) { int q = begin + atomicAdd(&lh[p2 >> 17], 1); col[q] = (int)(p2 & 0x1FFFFu); }
        if (i3 < end) { int q = begin + atomicAdd(&lh[p3 >> 17], 1); col[q] = (int)(p3 & 0x1FFFFu); }
    }
}

// ---------------- weight prep ----------------

__global__ void k_prepW(const float* __restrict__ Wc0, const float* __restrict__ Wc1,
                        const float* __restrict__ Wc2, const float* __restrict__ Wp,
                        const float* __restrict__ Ww,
                        short* __restrict__ outH, short* __restrict__ outL) {
    int c = blockIdx.x;
    const float* src;
    int koff = 0;
    if (c == 0) src = Wc0;
    else if (c == 1) src = Wc1;
    else if (c == 2) src = Wc2;
    else if (c < 6) { src = Wp; koff = (c - 3) * 128; }
    else { src = Ww; koff = (c - 6) * 128; }
    short* dh = outH + c * 16384;
    short* dl = outL + c * 16384;
    for (int i = threadIdx.x; i < 16384; i += 256) {
        int k = i >> 7, n = i & 127;
        float v = src[(size_t)(koff + k) * 128 + n];
        short h = f2bf(v);
        short l = f2bf(v - bf2f(h));
        dh[n * 128 + k] = h;
        dl[n * 128 + k] = l;
    }
}

// ---------------- split-bf16 MFMA GEMM ----------------
// if outb != nullptr: write bf16 (scaled, biased) instead of fp32 out.

__global__ __launch_bounds__(256) void k_mgemm(
    const float* __restrict__ A, const short* __restrict__ WTh,
    const short* __restrict__ WTl, float* __restrict__ out,
    short* __restrict__ outb, const int* __restrict__ gidx,
    const float* __restrict__ bias, const float* __restrict__ scale,
    int M, int accumulate) {
    __shared__ short Ah[64 * 128];
    __shared__ short Al[64 * 128];
    __shared__ short Bh[64 * 128];
    __shared__ short Bl[64 * 128];

    int t = threadIdx.x;
    int mtile = blockIdx.x >> 1, ntile = blockIdx.x & 1;
    int rowBase = mtile << 6;

#pragma unroll
    for (int j = 0; j < 8; ++j) {
        int row = (t >> 5) + (j << 3);
        int colf = (t & 31) << 2;
        int gr = rowBase + row;
        float4 v = make_float4(0.f, 0.f, 0.f, 0.f);
        if (gr < M) {
            long long ar = gidx ? (long long)gidx[gr] : (long long)gr;
            v = *(const float4*)&A[(size_t)ar * 128 + colf];
        }
        short4 hi, lo;
        hi.x = f2bf(v.x); lo.x = f2bf(v.x - bf2f(hi.x));
        hi.y = f2bf(v.y); lo.y = f2bf(v.y - bf2f(hi.y));
        hi.z = f2bf(v.z); lo.z = f2bf(v.z - bf2f(hi.z));
        hi.w = f2bf(v.w); lo.w = f2bf(v.w - bf2f(hi.w));
        unsigned off = (unsigned)(row << 8) + (((unsigned)(colf << 1)) ^ ((unsigned)((row & 7) << 4)));
        *(short4*)((char*)Ah + off) = hi;
        *(short4*)((char*)Al + off) = lo;
    }
#pragma unroll
    for (int j = 0; j < 4; ++j) {
        int c = (t >> 4) + (j << 4);
        int k8 = (t & 15) << 3;
        size_t goff = ((size_t)((ntile << 6) + c) << 7) + k8;
        bf16x8 wh = *(const bf16x8*)&WTh[goff];
        bf16x8 wl = *(const bf16x8*)&WTl[goff];
        unsigned off = (unsigned)(c << 8) + (((unsigned)(k8 << 1)) ^ ((unsigned)((c & 7) << 4)));
        *(bf16x8*)((char*)Bh + off) = wh;
        *(bf16x8*)((char*)Bl + off) = wl;
    }
    __syncthreads();

    int lane = t & 63;
    int wave = t >> 6;
    int wm = wave >> 1, wn = wave & 1;
    int l15 = lane & 15;
    int kq = (lane >> 4) << 4;

    fx4 acc[2][2];
#pragma unroll
    for (int i = 0; i < 2; ++i)
#pragma unroll
        for (int j = 0; j < 2; ++j) {
            acc[i][j][0] = 0.f; acc[i][j][1] = 0.f;
            acc[i][j][2] = 0.f; acc[i][j][3] = 0.f;
        }

    int ar0 = (wm << 5) + l15;
    int bc0 = (wn << 5) + l15;

#pragma unroll
    for (int k = 0; k < 4; ++k) {
        int kb = (k << 6) + kq;
        bf16x8 ah[2], al[2], bh[2], bl[2];
#pragma unroll
        for (int fr = 0; fr < 2; ++fr) {
            int r = ar0 + (fr << 4);
            unsigned off = (unsigned)(r << 8) + ((unsigned)kb ^ ((unsigned)((r & 7) << 4)));
            ah[fr] = *(const bf16x8*)((const char*)Ah + off);
            al[fr] = *(const bf16x8*)((const char*)Al + off);
        }
#pragma unroll
        for (int fc = 0; fc < 2; ++fc) {
            int c = bc0 + (fc << 4);
            unsigned off = (unsigned)(c << 8) + ((unsigned)kb ^ ((unsigned)((c & 7) << 4)));
            bh[fc] = *(const bf16x8*)((const char*)Bh + off);
            bl[fc] = *(const bf16x8*)((const char*)Bl + off);
        }
#pragma unroll
        for (int fr = 0; fr < 2; ++fr)
#pragma unroll
            for (int fc = 0; fc < 2; ++fc) {
                acc[fr][fc] = __builtin_amdgcn_mfma_f32_16x16x32_bf16(ah[fr], bh[fc], acc[fr][fc], 0, 0, 0);
                acc[fr][fc] = __builtin_amdgcn_mfma_f32_16x16x32_bf16(ah[fr], bl[fc], acc[fr][fc], 0, 0, 0);
                acc[fr][fc] = __builtin_amdgcn_mfma_f32_16x16x32_bf16(al[fr], bh[fc], acc[fr][fc], 0, 0, 0);
            }
    }

    int rq = (lane >> 4) << 2;
#pragma unroll
    for (int fr = 0; fr < 2; ++fr) {
#pragma unroll
        for (int fc = 0; fc < 2; ++fc) {
            int cg = (ntile << 6) + (wn << 5) + (fc << 4) + l15;
#pragma unroll
            for (int rg = 0; rg < 4; ++rg) {
                int r = rowBase + (wm << 5) + (fr << 4) + rq + rg;
                if (r < M) {
                    float v = acc[fr][fc][rg];
                    if (scale) v *= scale[r];
                    if (bias) v += bias[cg];
                    if (outb) {
                        outb[(size_t)r * 128 + cg] = f2bf(v);
                    } else {
                        size_t oo = (size_t)r * 128 + cg;
                        if (accumulate) v += out[oo];
                        out[oo] = v;
                    }
                }
            }
        }
    }
}

// ---------------- Aggregation over bf16 h': 4 lane-groups x 16 lanes x 16B ----------------
// xout[v] = relu(dinv[v]*(sum h'[col[e]] + h'[v]) + bias), h' bf16 pre-scaled rows.

__global__ __launch_bounds__(256) void k_agg(
    const short* __restrict__ h, const int* __restrict__ col,
    const int* __restrict__ offs, const float* __restrict__ dinv,
    const float* __restrict__ bias, float* __restrict__ xout, int n) {
    int lane = threadIdx.x & 63;
    int g = lane >> 4;
    int li = lane & 15;
    int v = (blockIdx.x << 2) + (threadIdx.x >> 6);
    if (v >= n) return;
    int beg = offs[v], end = offs[v + 1];
    float dv = dinv[v];
    float a[8];
#pragma unroll
    for (int j = 0; j < 8; ++j) a[j] = 0.f;
    if (g == 0) {
        bf16x8 hv = *(const bf16x8*)&h[(size_t)v * 128 + (li << 3)];
#pragma unroll
        for (int j = 0; j < 8; ++j) a[j] = bf2f(hv[j]);
    }
    int e = beg + g;
    for (; e + 4 < end; e += 8) {
        int sA = col[e], sB = col[e + 4];
        bf16x8 xA = *(const bf16x8*)&h[(size_t)sA * 128 + (li << 3)];
        bf16x8 xB = *(const bf16x8*)&h[(size_t)sB * 128 + (li << 3)];
#pragma unroll
        for (int j = 0; j < 8; ++j) a[j] += bf2f(xA[j]) + bf2f(xB[j]);
    }
    if (e < end) {
        bf16x8 xA = *(const bf16x8*)&h[(size_t)col[e] * 128 + (li << 3)];
#pragma unroll
        for (int j = 0; j < 8; ++j) a[j] += bf2f(xA[j]);
    }
#pragma unroll
    for (int off = 16; off <= 32; off <<= 1)
#pragma unroll
        for (int j = 0; j < 8; ++j) a[j] += __shfl_xor(a[j], off);
    if (g == 0) {
        float4 b0 = *(const float4*)&bias[li << 3];
        float4 b1 = *(const float4*)&bias[(li << 3) + 4];
        float4 o0, o1;
        o0.x = fmaxf(fmaf(a[0], dv, b0.x), 0.f);
        o0.y = fmaxf(fmaf(a[1], dv, b0.y), 0.f);
        o0.z = fmaxf(fmaf(a[2], dv, b0.z), 0.f);
        o0.w = fmaxf(fmaf(a[3], dv, b0.w), 0.f);
        o1.x = fmaxf(fmaf(a[4], dv, b1.x), 0.f);
        o1.y = fmaxf(fmaf(a[5], dv, b1.y), 0.f);
        o1.z = fmaxf(fmaf(a[6], dv, b1.z), 0.f);
        o1.w = fmaxf(fmaf(a[7], dv, b1.w), 0.f);
        float* op = &xout[(size_t)v * 128 + (li << 3)];
        *(float4*)op = o0;
        *(float4*)(op + 4) = o1;
    }
}

// ---------------- Final dot ----------------

__global__ __launch_bounds__(256) void k_dot(
    const float* __restrict__ P, const float* __restrict__ Q,
    float* __restrict__ out, int B) {
    int lane = threadIdx.x & 63;
    int b = (blockIdx.x << 2) + (threadIdx.x >> 6);
    if (b >= B) return;
    float2 p = *(const float2*)&P[(size_t)b * 128 + lane * 2];
    float2 q = *(const float2*)&Q[(size_t)b * 128 + lane * 2];
    float s = p.x * q.x + p.y * q.y;
#pragma unroll
    for (int off = 32; off; off >>= 1) s += __shfl_down(s, off);
    if (lane == 0) out[b] = s;
}

// ---------------- launch ----------------

extern "C" void kernel_launch(void* const* d_in, const int* in_sizes, int n_in,
                              void* d_out, int out_size, void* d_ws, size_t ws_size,
                              hipStream_t stream) {
    const float* x    = (const float*)d_in[0];
    const int*   edge = (const int*)d_in[1];
    const int*   sidx = (const int*)d_in[2];
    const int*   tidx = (const int*)d_in[3];
    const float* Wc0  = (const float*)d_in[4];
    const float* bc0  = (const float*)d_in[5];
    const float* Wc1  = (const float*)d_in[6];
    const float* bc1  = (const float*)d_in[7];
    const float* Wc2  = (const float*)d_in[8];
    const float* bc2  = (const float*)d_in[9];
    const float* Ww   = (const float*)d_in[10];
    const float* bw   = (const float*)d_in[11];
    const float* Wp   = (const float*)d_in[12];
    const float* bp   = (const float*)d_in[13];
    float* out = (float*)d_out;

    char* base = (char*)d_ws;
    size_t off = 0;
    auto alloc = [&](size_t bytes) -> char* {
        char* p = base + off;
        off = (off + bytes + 255) & ~(size_t)255;
        return p;
    };
    const size_t FSZ = (size_t)N_NODES * HID * sizeof(float);
    float* bufA    = (float*)alloc(FSZ);
    float* bufB    = (float*)alloc(FSZ);
    short* hbf     = (short*)alloc((size_t)N_NODES * HID * sizeof(short));
    float* Pm      = (float*)alloc((size_t)BATCH * HID * sizeof(float));
    float* Qm      = (float*)alloc((size_t)BATCH * HID * sizeof(float));
    int*   offsets = (int*)alloc((size_t)(N_NODES + 1) * sizeof(int));
    int*   colArr  = (int*)alloc((size_t)N_EDGES * sizeof(int));
    unsigned* tmp  = (unsigned*)alloc((size_t)N_EDGES * sizeof(unsigned));
    float* dinv    = (float*)alloc((size_t)N_NODES * sizeof(float));
    int*   bcnt    = (int*)alloc(256 * sizeof(int));
    int*   bbase   = (int*)alloc(256 * sizeof(int));
    int*   bcur    = (int*)alloc(256 * sizeof(int));
    short* wtH     = (short*)alloc((size_t)9 * 16384 * sizeof(short));
    short* wtL     = (short*)alloc((size_t)9 * 16384 * sizeof(short));
    (void)ws_size; (void)in_sizes; (void)n_in; (void)out_size;

    // ---- CSR build (bucketed) ----
    hipMemsetAsync(bcnt, 0, NB * sizeof(int), stream);
    k_bhist<<<(N_EDGES + 4095) / 4096, 256, 0, stream>>>(edge + N_EDGES, bcnt, N_EDGES);
    k_bscan<<<1, 256, 0, stream>>>(bcnt, bbase, bcur, offsets);
    k_passA<<<(N_EDGES + EPB - 1) / EPB, 256, 0, stream>>>(edge, bcur, tmp, N_EDGES);
    k_passB<<<NB, 256, 0, stream>>>(tmp, bbase, offsets, dinv, colArr);

    // ---- weight prep ----
    k_prepW<<<9, 256, 0, stream>>>(Wc0, Wc1, Wc2, Wp, Ww, wtH, wtL);

    const int gridN = ((N_NODES + 63) / 64) * 2;
    const int gridB = (BATCH / 64) * 2;
    const int aggGrid = (N_NODES + 3) / 4;
    const int dotGrid = (BATCH + 3) / 4;
#define WT(c) (wtH + (c) * 16384), (wtL + (c) * 16384)

    // ---- layer 1 ----
    k_mgemm<<<gridN, 256, 0, stream>>>(x, WT(0), nullptr, hbf, nullptr, nullptr, dinv, N_NODES, 0);
    k_agg<<<aggGrid, 256, 0, stream>>>(hbf, colArr, offsets, dinv, bc0, bufA, N_NODES);
    k_mgemm<<<gridB, 256, 0, stream>>>(bufA, WT(3), Pm, nullptr, sidx, bp, nullptr, BATCH, 0);
    k_mgemm<<<gridB, 256, 0, stream>>>(bufA, WT(6), Qm, nullptr, tidx, bw, nullptr, BATCH, 0);

    // ---- layer 2 ----
    k_mgemm<<<gridN, 256, 0, stream>>>(bufA, WT(1), nullptr, hbf, nullptr, nullptr, dinv, N_NODES, 0);
    k_agg<<<aggGrid, 256, 0, stream>>>(hbf, colArr, offsets, dinv, bc1, bufB, N_NODES);
    k_mgemm<<<gridB, 256, 0, stream>>>(bufB, WT(4), Pm, nullptr, sidx, nullptr, nullptr, BATCH, 1);
    k_mgemm<<<gridB, 256, 0, stream>>>(bufB, WT(7), Qm, nullptr, tidx, nullptr, nullptr, BATCH, 1);

    // ---- layer 3 ----
    k_mgemm<<<gridN, 256, 0, stream>>>(bufB, WT(2), nullptr, hbf, nullptr, nullptr, dinv, N_NODES, 0);
    k_agg<<<aggGrid, 256, 0, stream>>>(hbf, colArr, offsets, dinv, bc2, bufA, N_NODES);
    k_mgemm<<<gridB, 256, 0, stream>>>(bufA, WT(5), Pm, nullptr, sidx, nullptr, nullptr, BATCH, 1);
    k_mgemm<<<gridB, 256, 0, stream>>>(bufA, WT(8), Qm, nullptr, tidx, nullptr, nullptr, BATCH, 1);

    // ---- score ----
    k_dot<<<dotGrid, 256, 0, stream>>>(Pm, Qm, out, BATCH);
}